// Round 3
// baseline (158.406 us; speedup 1.0000x reference)
//
#include <hip/hip_runtime.h>
#include <hip/hip_bf16.h>

// Net_27358941675610: two-compartment rate net; the 50-step scan collapses to
//   R   = 0.35*sigmoid((6/7)*(psp^T @ W_h^T + b_h))            [4096,2048]
//   out = 0.35*sigmoid(0.75*(R @ W_o^T + b_o) + 0.125*label)   [4096,512]
// (0.3^t / 0.2^(50-t) transients are < 1e-25 at t=50 — fixed point is exact.)
// Inputs fp32, OUTPUT fp32 (R1 NaN proved fp32-sized inputs; R2 exact-refmax
// error proved d_out is read as fp32). Internal compute: bf16 MFMA, fp32 acc.

typedef __bf16 bf16_t;
typedef __bf16 bf16x8 __attribute__((ext_vector_type(8)));
typedef __bf16 bf16x4v __attribute__((ext_vector_type(4)));
typedef float f32x4 __attribute__((ext_vector_type(4)));

#define GLD_TO_LDS16(gp, lp)                                            \
  __builtin_amdgcn_global_load_lds(                                     \
      (__attribute__((address_space(1))) void*)(void*)(gp),             \
      (__attribute__((address_space(3))) void*)(lp), 16, 0, 0)

// ---- psp fp32 [R][C] -> pspT bf16 [C][R], 64x64 tiles --------------------
__global__ __launch_bounds__(256) void transpose_cvt(
    const float* __restrict__ in, bf16_t* __restrict__ out, int R, int C) {
  __shared__ float tile[64][65];
  const int tx = threadIdx.x & 63;
  const int ty = threadIdx.x >> 6;  // 0..3
  const int r0 = blockIdx.y * 64;
  const int c0 = blockIdx.x * 64;
#pragma unroll
  for (int i = 0; i < 16; ++i) {
    const int r = ty + i * 4;
    tile[r][tx] = in[(size_t)(r0 + r) * C + c0 + tx];
  }
  __syncthreads();
#pragma unroll
  for (int i = 0; i < 16; ++i) {
    const int r = ty + i * 4;
    out[(size_t)(c0 + r) * R + r0 + tx] = (bf16_t)tile[tx][r];
  }
}

// ---- contiguous fp32 -> bf16 downcast, 4 elems/thread --------------------
__global__ __launch_bounds__(256) void cvt_f32_bf16(
    const float4* __restrict__ in, bf16x4v* __restrict__ out, int n4) {
  const int i = blockIdx.x * 256 + threadIdx.x;
  if (i < n4) {
    const float4 v = in[i];
    bf16x4v o;
    o.x = (bf16_t)v.x; o.y = (bf16_t)v.y; o.z = (bf16_t)v.z; o.w = (bf16_t)v.w;
    out[i] = o;
  }
}

// ---- NT GEMM: C[M,N] = A[M,K] * Bt[N,K]^T, fused epilogue ----------------
// MODE 1: C(bf16) = 0.35*sigmoid((6/7)*(acc + bias[n]))
// MODE 2: C(fp32) = 0.35*sigmoid(0.75*(acc + bias[n]) + 0.125*lbl[m*N+n])
template <int BM, int BN, int WTM, int WTN, int MODE, typename OutT>
__global__ __launch_bounds__(256) void gemm_nt(
    const bf16_t* __restrict__ A, const bf16_t* __restrict__ Bt,
    const float* __restrict__ bias, const float* __restrict__ lbl,
    OutT* __restrict__ C, int M, int N, int K) {
  constexpr int BK = 32;
  __shared__ __align__(16) bf16_t sA[BM * BK];
  __shared__ __align__(16) bf16_t sB[BN * BK];

  const int tid = threadIdx.x;
  const int wave = tid >> 6;
  const int lane = tid & 63;
  const int bm = blockIdx.x * BM;
  const int bn = blockIdx.y * BN;
  const int wm = (wave & 1) * (WTM * 16);
  const int wn = (wave >> 1) * (WTN * 16);

  f32x4 acc[WTM][WTN] = {};

  const int srow = lane >> 2;  // row within 16-row staging chunk
  const int sseg = lane & 3;   // 16B segment within the 64B row
  const bf16_t* Ab = A + (size_t)bm * K;
  const bf16_t* Bb = Bt + (size_t)bn * K;

  const int fr = lane & 15;        // m (A) / n (B) within 16
  const int kq = (lane >> 4) * 8;  // k group base

  for (int k0 = 0; k0 < K; k0 += BK) {
    // stage A tile [BM][BK] row-major unpadded (wave-uniform LDS base)
#pragma unroll
    for (int c = 0; c < BM / 64; ++c) {
      const int chunk = wave + c * 4;  // 16 rows per chunk
      const bf16_t* gp = Ab + (size_t)(chunk * 16 + srow) * K + k0 + sseg * 8;
      GLD_TO_LDS16(gp, sA + chunk * 16 * BK);
    }
    // stage B tile [BN][BK]
#pragma unroll
    for (int c = 0; c < BN / 64; ++c) {
      const int chunk = wave + c * 4;
      const bf16_t* gp = Bb + (size_t)(chunk * 16 + srow) * K + k0 + sseg * 8;
      GLD_TO_LDS16(gp, sB + chunk * 16 * BK);
    }
    __syncthreads();  // drains vmcnt before ds_read

    bf16x8 af[WTM], bfr[WTN];
#pragma unroll
    for (int i = 0; i < WTM; ++i)
      af[i] = *(const bf16x8*)(sA + (wm + i * 16 + fr) * BK + kq);
#pragma unroll
    for (int j = 0; j < WTN; ++j)
      bfr[j] = *(const bf16x8*)(sB + (wn + j * 16 + fr) * BK + kq);
#pragma unroll
    for (int i = 0; i < WTM; ++i)
#pragma unroll
      for (int j = 0; j < WTN; ++j)
        acc[i][j] =
            __builtin_amdgcn_mfma_f32_16x16x32_bf16(af[i], bfr[j], acc[i][j], 0, 0, 0);
    __syncthreads();
  }

  // epilogue: C/D layout col = lane&15, row = (lane>>4)*4 + r  (m89)
  const int cm0 = (lane >> 4) * 4;
#pragma unroll
  for (int j = 0; j < WTN; ++j) {
    const int gn = bn + wn + j * 16 + fr;
    const float bj = bias[gn];
#pragma unroll
    for (int i = 0; i < WTM; ++i) {
#pragma unroll
      for (int r = 0; r < 4; ++r) {
        const int gm = bm + wm + i * 16 + cm0 + r;
        const float v = acc[i][j][r];
        float z;
        if (MODE == 1) {
          z = 0.8571428571428571f * (v + bj);
        } else {
          z = 0.75f * (v + bj) + 0.125f * lbl[(size_t)gm * N + gn];
        }
        const float s = 0.35f / (1.0f + __expf(-z));
        C[(size_t)gm * N + gn] = (OutT)s;
      }
    }
  }
}

extern "C" void kernel_launch(void* const* d_in, const int* in_sizes, int n_in,
                              void* d_out, int out_size, void* d_ws, size_t ws_size,
                              hipStream_t stream) {
  constexpr int IN = 1024, HID = 2048, OUT = 512, B = 4096;
  const float* psp = (const float*)d_in[0];   // [IN, B]  fp32
  const float* lbl = (const float*)d_in[1];   // [B, OUT] fp32
  const float* W_h = (const float*)d_in[2];   // [HID, IN] fp32
  const float* b_h = (const float*)d_in[3];   // [HID] fp32
  const float* W_o = (const float*)d_in[4];   // [OUT, HID] fp32
  const float* b_o = (const float*)d_in[5];   // [OUT] fp32
  float* out = (float*)d_out;                 // [B, OUT] fp32

  bf16_t* pspT = (bf16_t*)d_ws;               // [B, IN]    8 MB
  bf16_t* Whb = pspT + (size_t)B * IN;        // [HID, IN]  4 MB
  bf16_t* Wob = Whb + (size_t)HID * IN;       // [OUT, HID] 2 MB
  bf16_t* Rm = Wob + (size_t)OUT * HID;       // [B, HID]  16 MB

  // psp [IN,B] fp32 -> pspT [B,IN] bf16
  transpose_cvt<<<dim3(B / 64, IN / 64), 256, 0, stream>>>(psp, pspT, IN, B);
  // weights fp32 -> bf16 (already K-contiguous for the NT GEMM)
  cvt_f32_bf16<<<(HID * IN / 4 + 255) / 256, 256, 0, stream>>>(
      (const float4*)W_h, (bf16x4v*)Whb, HID * IN / 4);
  cvt_f32_bf16<<<(OUT * HID / 4 + 255) / 256, 256, 0, stream>>>(
      (const float4*)W_o, (bf16x4v*)Wob, OUT * HID / 4);
  // R = 0.35*sigmoid((6/7)*(pspT @ W_h^T + b_h))   (bf16 intermediate)
  gemm_nt<128, 128, 4, 4, 1, bf16_t><<<dim3(B / 128, HID / 128), 256, 0, stream>>>(
      pspT, Whb, b_h, nullptr, Rm, B, HID, IN);
  // out = 0.35*sigmoid(0.75*(R @ W_o^T + b_o) + 0.125*label)   (fp32 out)
  gemm_nt<128, 64, 4, 2, 2, float><<<dim3(B / 128, OUT / 64), 256, 0, stream>>>(
      Rm, Wob, b_o, lbl, out, B, OUT, HID);
}